// Round 5
// baseline (326.215 us; speedup 1.0000x reference)
//
#include <hip/hip_runtime.h>

// ---------------- problem constants ----------------
constexpr int Nn   = 100000;   // nodes
constexpr int Ee   = 1600000;  // edges
constexpr int D    = 128;      // hidden = input dim
constexpr int DOUT = 40;       // classifier out
constexpr int DCAT = 384;      // 3*D concat width
constexpr int CPAD = 48;       // DOUT padded to 3x16 MFMA col tiles
constexpr int WS   = 392;      // Wct row stride (halfs)

// binned-sort parameters
constexpr int BINSH  = 8;                          // 256 nodes per bin
constexpr int BINSZ  = 1 << BINSH;
constexpr int BINS   = (Nn + BINSZ - 1) / BINSZ;   // 391
constexpr int CHUNK  = 8192;                       // edges per scatter block
constexpr int NCHUNK = (Ee + CHUNK - 1) / CHUNK;   // 196
constexpr int SEGCAP = 5376;                       // max edges/bin (mean 4092, +20 sigma)
constexpr int PADCAP = SEGCAP + 7 * BINSZ;         // 7168: per-bin padded arena stride

typedef _Float16 f16;
typedef _Float16 f16x2 __attribute__((ext_vector_type(2)));
typedef _Float16 f16x8 __attribute__((ext_vector_type(8)));
typedef float    f32x4 __attribute__((ext_vector_type(4)));

// ---------------- edge dtype detect ----------------
__global__ void detect_layout(const int* __restrict__ ei, int* __restrict__ flag) {
    if (threadIdx.x == 0 && blockIdx.x == 0) {
        unsigned orv = 0;
        for (int j = 0; j < 256; ++j) orv |= (unsigned)ei[2 * j + 1];
        *flag = (orv == 0u) ? 1 : 0;  // 1 => int64 layout
    }
}

__device__ inline void load_edge(const int* __restrict__ ei, int f, int e, int& s, int& d) {
    if (f) {  // int64: read 8B, use low word
        s = ((const int2*)ei)[e].x;
        d = ((const int2*)ei)[Ee + e].x;
    } else {
        s = ei[e];
        d = ei[Ee + e];
    }
}

// inclusive Hillis-Steele scan of n2 (<=512) ints with 256 threads, double-buffered.
__device__ inline int* scan_incl(int* pa, int* pb, int n2, int tid) {
    for (int off = 1; off < n2; off <<= 1) {
        for (int i = tid; i < n2; i += 256) pb[i] = pa[i] + ((i >= off) ? pa[i - off] : 0);
        __syncthreads();
        int* t = pa; pa = pb; pb = t;
    }
    return pa;
}

// ---------------- P1: per-bin edge histogram ----------------
__global__ __launch_bounds__(256) void bin_hist(const int* __restrict__ ei,
                                                const int* __restrict__ flag,
                                                int* __restrict__ binCnt) {
    __shared__ int h[BINS];
    for (int i = threadIdx.x; i < BINS; i += 256) h[i] = 0;
    __syncthreads();
    int f = *flag;
    for (int e = blockIdx.x * 256 + threadIdx.x; e < Ee; e += gridDim.x * 256) {
        int s, d;
        load_edge(ei, f, e, s, d);
        if ((unsigned)s < (unsigned)Nn && (unsigned)d < (unsigned)Nn)
            atomicAdd(&h[d >> BINSH], 1);
    }
    __syncthreads();
    for (int i = threadIdx.x; i < BINS; i += 256)
        if (h[i]) atomicAdd(&binCnt[i], h[i]);
}

// ---------------- P2: scan bins -> arena offsets + cursors ----------------
__global__ __launch_bounds__(512) void bin_scan(const int* __restrict__ binCnt,
                                                int* __restrict__ binOff,
                                                int* __restrict__ binCursor) {
    __shared__ int a[512];
    int t = threadIdx.x;
    int v = (t < BINS) ? binCnt[t] : 0;
    a[t] = v;
    __syncthreads();
    for (int off = 1; off < 512; off <<= 1) {
        int x = a[t] + ((t >= off) ? a[t - off] : 0);
        __syncthreads();
        a[t] = x;
        __syncthreads();
    }
    if (t < BINS) { binOff[t] = a[t] - v; binCursor[t] = a[t] - v; }
    if (t == 0) binOff[BINS] = a[BINS - 1];
}

// ---------------- P3: binning scatter (coalesced run writes) ----------------
__global__ __launch_bounds__(256) void bin_scatter(const int* __restrict__ ei,
                                                   const int* __restrict__ flag,
                                                   int* __restrict__ binCursor,
                                                   unsigned* __restrict__ arena) {
    __shared__ unsigned srec[CHUNK];                       // 32 KB
    __shared__ int bcnt[BINS], bpfx[BINS], bfill[BINS], gbase[BINS];
    __shared__ int pA[512], pB[512];
    const int tid = threadIdx.x;
    const int e0 = blockIdx.x * CHUNK;
    const int n = min(CHUNK, Ee - e0);
    const int f = *flag;

    for (int i = tid; i < BINS; i += 256) { bcnt[i] = 0; bfill[i] = 0; }
    __syncthreads();
    for (int i = tid; i < n; i += 256) {
        int s, d;
        load_edge(ei, f, e0 + i, s, d);
        if ((unsigned)s < (unsigned)Nn && (unsigned)d < (unsigned)Nn)
            atomicAdd(&bcnt[d >> BINSH], 1);
    }
    __syncthreads();
    for (int i = tid; i < 512; i += 256) pA[i] = (i < BINS) ? bcnt[i] : 0;
    __syncthreads();
    int* incl = scan_incl(pA, pB, 512, tid);
    for (int i = tid; i < BINS; i += 256) {
        bpfx[i] = incl[i] - bcnt[i];
        gbase[i] = bcnt[i] ? atomicAdd(&binCursor[i], bcnt[i]) : 0;
    }
    __syncthreads();
    for (int i = tid; i < n; i += 256) {
        int s, d;
        load_edge(ei, f, e0 + i, s, d);
        if ((unsigned)s < (unsigned)Nn && (unsigned)d < (unsigned)Nn) {
            int bin = d >> BINSH;
            int lp = atomicAdd(&bfill[bin], 1);
            srec[bpfx[bin] + lp] = ((unsigned)(d & (BINSZ - 1)) << 17) | (unsigned)s;
        }
    }
    __syncthreads();
    const int wid = tid >> 6, lane = tid & 63;
    for (int bin = wid; bin < BINS; bin += 4) {
        int cnt = bcnt[bin], off = bpfx[bin], gb = gbase[bin];
        for (int j = lane; j < cnt; j += 64) arena[gb + j] = srec[off + j];
    }
}

// ---------------- P4: per-bin finalize -> PADDED CSR (+deg, dinv) ----------------
// Each node's list padded to a multiple of 8 with sentinel Nn (the zero row).
__global__ __launch_bounds__(256) void bin_finalize(const int* __restrict__ binOff,
                                                    const unsigned* __restrict__ arena,
                                                    int* __restrict__ rowPtrPad,
                                                    int* __restrict__ deg,
                                                    float* __restrict__ dinv,
                                                    int* __restrict__ sortedSrc) {
    __shared__ unsigned seg[SEGCAP];   // 21 KB
    __shared__ int ssrc[PADCAP];       // 28.7 KB
    __shared__ int cnt[BINSZ], fill[BINSZ], pA[BINSZ], pB[BINSZ];
    const int tid = threadIdx.x;
    const int b = blockIdx.x;
    const int base = binOff[b];
    int len = binOff[b + 1] - base;
    if (len > SEGCAP) len = SEGCAP;

    for (int i = tid; i < len; i += 256) seg[i] = arena[base + i];
    for (int i = tid; i < BINSZ; i += 256) { cnt[i] = 0; fill[i] = 0; }
    __syncthreads();
    for (int i = tid; i < len; i += 256) atomicAdd(&cnt[seg[i] >> 17], 1);
    __syncthreads();
    for (int i = tid; i < BINSZ; i += 256) pA[i] = (cnt[i] + 7) & ~7;  // padded counts
    __syncthreads();
    int* incl = scan_incl(pA, pB, BINSZ, tid);

    const int node0 = b * BINSZ;
    const int padLen = incl[BINSZ - 1];
    for (int t = tid; t < BINSZ; t += 256) {
        int node = node0 + t;
        if (node < Nn) {
            int pc = (cnt[t] + 7) & ~7;
            rowPtrPad[node] = b * PADCAP + incl[t] - pc;
            deg[node] = cnt[t];
            dinv[node] = rsqrtf((float)(cnt[t] + 1));  // +1 self loop
        }
    }
    for (int i = tid; i < padLen; i += 256) ssrc[i] = Nn;  // sentinel -> zero row
    __syncthreads();
    for (int i = tid; i < len; i += 256) {
        unsigned r = seg[i];
        int dl = r >> 17, s = (int)(r & 0x1FFFFu);
        int pc = (cnt[dl] + 7) & ~7;
        int p = atomicAdd(&fill[dl], 1);
        ssrc[incl[dl] - pc + p] = s;
    }
    __syncthreads();
    for (int i = tid; i < padLen; i += 256) sortedSrc[(size_t)b * PADCAP + i] = ssrc[i];
}

// ---------------- W transpose + fp16 convert: Wt[c][k] = W[k][c] (conv weights) ----------------
__global__ __launch_bounds__(256) void transpose_w(const float* __restrict__ W0,
                                                   const float* __restrict__ W1,
                                                   const float* __restrict__ W2,
                                                   f16* __restrict__ T) {
    const float* W = (blockIdx.x == 0) ? W0 : ((blockIdx.x == 1) ? W1 : W2);
    f16* Wt = T + (size_t)blockIdx.x * D * D;
    for (int i = threadIdx.x; i < D * D; i += 256) {
        int k = i >> 7, c = i & 127;
        Wt[c * D + k] = (f16)W[i];
    }
}

// ---------------- W_cls transpose+pad: Wct[c][k] (c<48 padded, stride WS) ----------------
__global__ __launch_bounds__(256) void prep_wcls(const float* __restrict__ Wc,
                                                 f16* __restrict__ Wct) {
    for (int i = threadIdx.x; i < CPAD * WS; i += 256) {
        int c = i / WS, k = i - c * WS;
        f16 v = (f16)0.0f;
        if (c < DOUT && k < DCAT) v = (f16)Wc[k * DOUT + c];
        Wct[i] = v;
    }
}

// ---------------- MFMA GEMM: C[M,128](f16,stride sC) = act(A[M,128,stride sA] @ Wt^T (+bias)) * scale ----
template <int AFP32>
__global__ __launch_bounds__(256) void gemm_mfma(const void* __restrict__ Ain, int sA,
                                                 const f16* __restrict__ Wt,
                                                 const float* __restrict__ bias,
                                                 const float* __restrict__ scale,
                                                 f16* __restrict__ C, int sC,
                                                 int M, int doRelu) {
    __shared__ f16 Bsw[128 * 128];  // 32 KB
    const int tid = threadIdx.x;
    const int r0 = blockIdx.x * 128;

    {   // stage B
        int row = tid >> 1, half = (tid & 1) * 128;
#pragma unroll
        for (int i = 0; i < 8; ++i) {
            int bir = half + i * 16;
            uint4 v = *(const uint4*)((const char*)Wt + (size_t)row * 256 + bir);
            *(uint4*)((char*)Bsw + row * 256 + (bir ^ ((row & 7) << 4))) = v;
        }
    }
    __syncthreads();

    const int lane = tid & 63;
    const int w    = tid >> 6;
    const int wr   = w * 32;

    f32x4 acc[2][8];
#pragma unroll
    for (int mf = 0; mf < 2; ++mf)
#pragma unroll
        for (int nf = 0; nf < 8; ++nf) acc[mf][nf] = (f32x4){0, 0, 0, 0};

#pragma unroll
    for (int kk = 0; kk < 4; ++kk) {
        const int ke = kk * 32 + (lane >> 4) * 8;  // k element offset for this lane
        f16x8 a[2], b[8];
#pragma unroll
        for (int mf = 0; mf < 2; ++mf) {
            int row = r0 + wr + mf * 16 + (lane & 15);
            int rc = (row < M) ? row : (M - 1);  // clamp; OOB rows never stored
            if (AFP32) {
                const float* p = (const float*)Ain + (size_t)rc * sA + ke;
                float4 f0 = *(const float4*)p;
                float4 f1 = *(const float4*)(p + 4);
                f16x8 h;
                h[0] = (f16)f0.x; h[1] = (f16)f0.y; h[2] = (f16)f0.z; h[3] = (f16)f0.w;
                h[4] = (f16)f1.x; h[5] = (f16)f1.y; h[6] = (f16)f1.z; h[7] = (f16)f1.w;
                a[mf] = h;
            } else {
                a[mf] = *(const f16x8*)((const f16*)Ain + (size_t)rc * sA + ke);
            }
        }
#pragma unroll
        for (int nf = 0; nf < 8; ++nf) {
            int col = nf * 16 + (lane & 15);
            int bir = kk * 64 + (lane >> 4) * 16;
            b[nf] = *(const f16x8*)((const char*)Bsw + col * 256 + (bir ^ ((col & 7) << 4)));
        }
#pragma unroll
        for (int mf = 0; mf < 2; ++mf)
#pragma unroll
            for (int nf = 0; nf < 8; ++nf)
                acc[mf][nf] = __builtin_amdgcn_mfma_f32_16x16x32_f16(a[mf], b[nf], acc[mf][nf], 0, 0, 0);
    }

    float bv[8];
#pragma unroll
    for (int nf = 0; nf < 8; ++nf) bv[nf] = bias ? bias[nf * 16 + (lane & 15)] : 0.0f;
#pragma unroll
    for (int mf = 0; mf < 2; ++mf) {
#pragma unroll
        for (int i = 0; i < 4; ++i) {
            int row = r0 + wr + mf * 16 + (lane >> 4) * 4 + i;
            if (row < M) {
                float sc = scale ? scale[row] : 1.0f;
#pragma unroll
                for (int nf = 0; nf < 8; ++nf) {
                    float v = acc[mf][nf][i] + bv[nf];
                    if (doRelu && v < 0.0f) v = 0.0f;
                    C[(size_t)row * sC + nf * 16 + (lane & 15)] = (f16)(v * sc);
                }
            }
        }
    }
}

// ---------------- padded-CSR aggregation: no masks, pk_add_f16 trees ----------------
// hcat[i][partOff..] = relu( dinv[i] * ( sum_{s in Npad(i)} tmp[s] + tmp[i] ) + b )
// tmp row Nn is all-zero (sentinel target for padded slots).
__global__ __launch_bounds__(256) void aggregate_pad(const f16* __restrict__ tmp,
                                                     const int* __restrict__ rowPtrPad,
                                                     const int* __restrict__ deg,
                                                     const int* __restrict__ sortedSrc,
                                                     const float* __restrict__ dinv,
                                                     const float* __restrict__ bias,
                                                     f16* __restrict__ hcat, int partOff) {
    int node = (blockIdx.x * 256 + threadIdx.x) >> 6;  // one wave per node
    int lane = threadIdx.x & 63;
    if (node >= Nn) return;
    const f16x2* t2 = (const f16x2*)tmp;

    int base = rowPtrPad[node];
    int pc = (deg[node] + 7) & ~7;
    float di = dinv[node];

    f16x2 sv = t2[(size_t)node * 64 + lane];  // self (already *dinv[node])
    float ax = (float)sv[0];
    float ay = (float)sv[1];

    for (int e = 0; e < pc; e += 8) {
        int4 ia = *(const int4*)(sortedSrc + base + e);
        int4 ib = *(const int4*)(sortedSrc + base + e + 4);
        f16x2 g0 = t2[(size_t)ia.x * 64 + lane];
        f16x2 g1 = t2[(size_t)ia.y * 64 + lane];
        f16x2 g2 = t2[(size_t)ia.z * 64 + lane];
        f16x2 g3 = t2[(size_t)ia.w * 64 + lane];
        f16x2 g4 = t2[(size_t)ib.x * 64 + lane];
        f16x2 g5 = t2[(size_t)ib.y * 64 + lane];
        f16x2 g6 = t2[(size_t)ib.z * 64 + lane];
        f16x2 g7 = t2[(size_t)ib.w * 64 + lane];
        // depth-2 fp16 trees (<=4 terms in fp16), flush to fp32
        f16x2 s0 = g0 + g1, s1 = g2 + g3, s2 = g4 + g5, s3 = g6 + g7;
        f16x2 s4 = s0 + s1, s5 = s2 + s3;
        ax += (float)s4[0] + (float)s5[0];
        ay += (float)s4[1] + (float)s5[1];
    }

    float2 bb = ((const float2*)bias)[lane];
    ax = di * ax + bb.x;
    ay = di * ay + bb.y;
    if (ax < 0.0f) ax = 0.0f;
    if (ay < 0.0f) ay = 0.0f;
    f16x2 o;
    o[0] = (f16)ax;
    o[1] = (f16)ay;
    *(f16x2*)(hcat + (size_t)node * DCAT + partOff + lane * 2) = o;
}

// ---------------- MFMA classifier: out[N,40] = hcat[N,384] @ Wct^T + b ----------------
__global__ __launch_bounds__(256) void cls_mfma(const f16* __restrict__ hcat,
                                                const f16* __restrict__ Wct,
                                                const float* __restrict__ bc,
                                                float* __restrict__ out) {
    __shared__ f16 Bs[CPAD * WS];  // 37.6 KB
    const int tid = threadIdx.x;
    for (int i = tid; i < CPAD * WS / 8; i += 256)
        ((uint4*)Bs)[i] = ((const uint4*)Wct)[i];
    __syncthreads();

    const int lane = tid & 63;
    const int w    = tid >> 6;
    const int r0   = blockIdx.x * 128 + w * 32;

    f32x4 acc[2][3];
#pragma unroll
    for (int mf = 0; mf < 2; ++mf)
#pragma unroll
        for (int nf = 0; nf < 3; ++nf) acc[mf][nf] = (f32x4){0, 0, 0, 0};

#pragma unroll 3
    for (int kk = 0; kk < 12; ++kk) {
        const int ke = kk * 32 + (lane >> 4) * 8;
        f16x8 a[2], b[3];
#pragma unroll
        for (int mf = 0; mf < 2; ++mf) {
            int row = r0 + mf * 16 + (lane & 15);
            int rc = (row < Nn) ? row : (Nn - 1);
            a[mf] = *(const f16x8*)(hcat + (size_t)rc * DCAT + ke);
        }
#pragma unroll
        for (int nf = 0; nf < 3; ++nf) {
            int col = nf * 16 + (lane & 15);
            b[nf] = *(const f16x8*)(Bs + col * WS + ke);
        }
#pragma unroll
        for (int mf = 0; mf < 2; ++mf)
#pragma unroll
            for (int nf = 0; nf < 3; ++nf)
                acc[mf][nf] = __builtin_amdgcn_mfma_f32_16x16x32_f16(a[mf], b[nf], acc[mf][nf], 0, 0, 0);
    }

    float bv[3];
#pragma unroll
    for (int nf = 0; nf < 3; ++nf) {
        int col = nf * 16 + (lane & 15);
        bv[nf] = (col < DOUT) ? bc[col] : 0.0f;
    }
#pragma unroll
    for (int mf = 0; mf < 2; ++mf) {
#pragma unroll
        for (int i = 0; i < 4; ++i) {
            int row = r0 + mf * 16 + (lane >> 4) * 4 + i;
            if (row < Nn) {
#pragma unroll
                for (int nf = 0; nf < 3; ++nf) {
                    int col = nf * 16 + (lane & 15);
                    if (col < DOUT) out[(size_t)row * DOUT + col] = acc[mf][nf][i] + bv[nf];
                }
            }
        }
    }
}

// ---------------- launch ----------------
extern "C" void kernel_launch(void* const* d_in, const int* in_sizes, int n_in,
                              void* d_out, int out_size, void* d_ws, size_t ws_size,
                              hipStream_t stream) {
    const float* x       = (const float*)d_in[0];
    const int*   ei      = (const int*)d_in[1];
    const float* W_embed = (const float*)d_in[2];
    const float* b_embed = (const float*)d_in[3];
    const float* W_conv1 = (const float*)d_in[4];
    const float* b_conv1 = (const float*)d_in[5];
    const float* W_conv2 = (const float*)d_in[6];
    const float* b_conv2 = (const float*)d_in[7];
    const float* W_cls   = (const float*)d_in[8];
    const float* b_cls   = (const float*)d_in[9];
    float* out = (float*)d_out;

    char* p = (char*)d_ws;
    size_t o = 0;
    auto carve = [&](size_t bytes) {
        char* r = p + o;
        o = (o + bytes + 255) & ~(size_t)255;
        return r;
    };
    int*      binCnt    = (int*)carve((size_t)BINS * 4);
    int*      binOff    = (int*)carve((size_t)(BINS + 1) * 4);
    int*      binCursor = (int*)carve((size_t)BINS * 4);
    unsigned* arena     = (unsigned*)carve((size_t)Ee * 4);
    int*      rowPtrPad = (int*)carve((size_t)Nn * 4);
    int*      deg       = (int*)carve((size_t)Nn * 4);
    int*      sortedSrc = (int*)carve((size_t)BINS * PADCAP * 4);  // 11.2 MB
    float*    dinv      = (float*)carve((size_t)Nn * 4);
    int*      flag      = (int*)carve(4);
    f16*      WtAll     = (f16*)carve((size_t)3 * D * D * 2);
    f16*      Wct       = (f16*)carve((size_t)CPAD * WS * 2);
    f16*      hcat      = (f16*)carve((size_t)Nn * DCAT * 2);      // 76.8 MB
    f16*      tmp       = (f16*)carve((size_t)(Nn + 1) * D * 2);   // +1 zero row
    (void)ws_size;

    hipMemsetAsync(binCnt, 0, (size_t)BINS * 4, stream);
    hipMemsetAsync(tmp + (size_t)Nn * D, 0, D * 2, stream);  // sentinel zero row
    detect_layout<<<1, 64, 0, stream>>>(ei, flag);
    bin_hist<<<512, 256, 0, stream>>>(ei, flag, binCnt);
    bin_scan<<<1, 512, 0, stream>>>(binCnt, binOff, binCursor);
    bin_scatter<<<NCHUNK, 256, 0, stream>>>(ei, flag, binCursor, arena);
    bin_finalize<<<BINS, 256, 0, stream>>>(binOff, arena, rowPtrPad, deg, dinv, sortedSrc);
    transpose_w<<<3, 256, 0, stream>>>(W_embed, W_conv1, W_conv2, WtAll);
    prep_wcls<<<1, 256, 0, stream>>>(W_cls, Wct);

    const int gGemm = (Nn + 127) / 128;
    const int gAgg  = (Nn * 64) / 256;

    // h0 = relu(x @ W_embed + b_embed)  -> hcat part 0
    gemm_mfma<1><<<gGemm, 256, 0, stream>>>(x, D, WtAll, b_embed, nullptr, hcat, DCAT, Nn, 1);
    // conv1: tmp = (h0 @ W1) * dinv ; h1 = relu(dinv*(agg+self) + b1) -> hcat part 1
    gemm_mfma<0><<<gGemm, 256, 0, stream>>>(hcat, DCAT, WtAll + D * D, nullptr, dinv, tmp, D, Nn, 0);
    aggregate_pad<<<gAgg, 256, 0, stream>>>(tmp, rowPtrPad, deg, sortedSrc, dinv, b_conv1, hcat, D);
    // conv2 -> hcat part 2
    gemm_mfma<0><<<gGemm, 256, 0, stream>>>(hcat + D, DCAT, WtAll + 2 * D * D, nullptr, dinv, tmp, D, Nn, 0);
    aggregate_pad<<<gAgg, 256, 0, stream>>>(tmp, rowPtrPad, deg, sortedSrc, dinv, b_conv2, hcat, 2 * D);
    // classifier (MFMA over concat)
    cls_mfma<<<gGemm, 256, 0, stream>>>(hcat, Wct, b_cls, out);
}